// Round 10
// baseline (99.371 us; speedup 1.0000x reference)
//
#include <hip/hip_runtime.h>
#include <hip/hip_bf16.h>

typedef __attribute__((ext_vector_type(8))) short short8;
typedef __attribute__((ext_vector_type(4))) short short4v;
typedef __attribute__((ext_vector_type(4))) float f32x4;

// ws: A' [8192][128] bf16 (2MB) | B' [8192][128] bf16 (2MB) |
//     WoutT [128][1024] bf16 (256KB) | W12bf [64][256] bf16 (32KB)
#define WS_A   0
#define WS_B   (8192 * 128 * 2)
#define WS_WT  (2 * 8192 * 128 * 2)
#define WS_W12 (WS_WT + 128 * 1024 * 2)

static __device__ __forceinline__ short f2bf(float x) {
    __hip_bfloat16 h = __float2bfloat16(x);
    return *reinterpret_cast<short*>(&h);
}

typedef __attribute__((address_space(3))) unsigned int lds_u32;
typedef const __attribute__((address_space(1))) unsigned int glb_u32;
static __device__ __forceinline__ void stage16(const void* g, void* l) {
    __builtin_amdgcn_global_load_lds((glb_u32*)g, (lds_u32*)l, 16, 0, 0);
}

// ---------------- Kernel 0: Wout -> bf16 [z][ck]; W1|W2 -> bf16 [64 c][256 d] ----------------
__global__ __launch_bounds__(256) void k_prep(const float* __restrict__ Wout,
                                              const float* __restrict__ W1,
                                              const float* __restrict__ W2,
                                              __hip_bfloat16* __restrict__ WoutT,
                                              __hip_bfloat16* __restrict__ W12bf) {
    int idx = blockIdx.x * 256 + threadIdx.x;
    if (blockIdx.x < 512) {
        int z = idx >> 10, ck = idx & 1023;
        WoutT[idx] = __float2bfloat16(Wout[ck * 128 + z]);
    } else {
        idx -= 512 * 256;                  // 0..16383
        int c = idx >> 8, d = idx & 255;
        W12bf[idx] = __float2bfloat16(c < 32 ? W1[d * 32 + c] : W2[d * 32 + (c - 32)]);
    }
}

// ---------------- Kernel 1: LayerNorm + dual projection via MFMA (unchanged) ----------------
__global__ __launch_bounds__(256) void k_lnproj(const float* __restrict__ mm,
                                                const float* __restrict__ gamma,
                                                const float* __restrict__ beta,
                                                const float* __restrict__ b1,
                                                const float* __restrict__ b2,
                                                const __hip_bfloat16* __restrict__ W12bf,
                                                __hip_bfloat16* __restrict__ Ap,
                                                __hip_bfloat16* __restrict__ Bp) {
    __shared__ char sMN[4][8192];      // per-wave [16 rows][256 d] bf16, XOR-swizzled
    __shared__ char sW[32768];         // [64 c][256 d] bf16, XOR-swizzled (512B rows)
    const int t    = threadIdx.x;
    const int lane = t & 63;
    const int wid  = t >> 6;
    const int gw   = blockIdx.x * 4 + wid;   // 0..2047
    const int i_   = gw & 255;
    const int sb   = (gw >> 8) * 16;

    #pragma unroll
    for (int it = 0; it < 8; it++) {
        const int idx = it * 256 + t;
        const int row = idx >> 5;
        const int L   = (idx & 31) * 16;
        *(short8*)(sW + row * 512 + (L ^ ((row & 7) << 4))) =
            *(const short8*)((const short*)W12bf + idx * 8);
    }

    float4 g4  = *(const float4*)&gamma[lane * 4];
    float4 be4 = *(const float4*)&beta[lane * 4];
    char* my = sMN[wid];

    #pragma unroll
    for (int rr = 0; rr < 16; rr++) {
        float4 x = *(const float4*)&mm[((size_t)(sb + rr) * 256 + i_) * 256 + lane * 4];
        float s  = x.x + x.y + x.z + x.w;
        float ss = x.x * x.x + x.y * x.y + x.z * x.z + x.w * x.w;
        #pragma unroll
        for (int off = 32; off; off >>= 1) {
            s  += __shfl_xor(s, off);
            ss += __shfl_xor(ss, off);
        }
        float mu  = s * (1.f / 256.f);
        float var = ss * (1.f / 256.f) - mu * mu;
        float rs  = rsqrtf(var + 1e-5f);
        short4v v;
        v.x = f2bf((x.x - mu) * rs * g4.x + be4.x);
        v.y = f2bf((x.y - mu) * rs * g4.y + be4.y);
        v.z = f2bf((x.z - mu) * rs * g4.z + be4.z);
        v.w = f2bf((x.w - mu) * rs * g4.w + be4.w);
        *(short4v*)(my + rr * 512 + ((lane * 8) ^ ((rr & 7) << 4))) = v;
    }
    __syncthreads();

    const int g = lane >> 4, r16 = lane & 15;

    f32x4 acc[4];
    #pragma unroll
    for (int nf = 0; nf < 4; nf++) {
        int col = nf * 16 + r16;
        float bv = (col < 32) ? b1[col] : b2[col - 32];
        acc[nf] = (f32x4){bv, bv, bv, bv};
    }
    #pragma unroll
    for (int ks = 0; ks < 8; ks++) {
        const int L = ks * 64 + g * 16;
        short8 af = *(const short8*)(my + r16 * 512 + (L ^ ((r16 & 7) << 4)));
        #pragma unroll
        for (int nf = 0; nf < 4; nf++) {
            short8 bfv = *(const short8*)(sW + (nf * 16 + r16) * 512 + (L ^ ((r16 & 7) << 4)));
            acc[nf] = __builtin_amdgcn_mfma_f32_16x16x32_bf16(af, bfv, acc[nf], 0, 0, 0);
        }
    }
    #pragma unroll
    for (int nf = 0; nf < 4; nf++) {
        int col = nf * 16 + r16;
        short* Out = (short*)((col < 32) ? Ap : Bp);
        int cr = col & 31;
        short4v v;
        v.x = f2bf(acc[nf][0]); v.y = f2bf(acc[nf][1]);
        v.z = f2bf(acc[nf][2]); v.w = f2bf(acc[nf][3]);
        *(short4v*)&Out[(i_ * 32 + cr) * 128 + sb + g * 4] = v;
    }
}

// ---------------- Kernel 2: gemm6 structure + pipe-balanced (2pg x 4zg) epilogue ----------
// LDS (128KB dyn): staging kh0 [0,64K) (B|A), kh1 [64K,128K). After main: sP h0 [0,64K),
// sP h1 [64K,128K) ([64 p][512 ck'] each, key ((L>>7)^p)&7).
// EPI: wave = (zgi = wid>>1, pg = wid&1): 32 p-rows x 32 z; sP mult 4, W mult 2.
extern __shared__ char lds[];

__global__ __launch_bounds__(512, 1) void k_gemm10(const __hip_bfloat16* __restrict__ Apb,
                                                   const __hip_bfloat16* __restrict__ Bpb,
                                                   const __hip_bfloat16* __restrict__ WoutT,
                                                   const float* __restrict__ bout,
                                                   float* __restrict__ out) {
    const int t = threadIdx.x, lane = t & 63, wid = t >> 6;
    const int g = lane >> 4, r16 = lane & 15;
    const int wr = wid >> 2, wc = wid & 3;            // wr: jk half (2), wc: ic quarter (4)
    const int bid = (blockIdx.x & 7) * 128 + (blockIdx.x >> 3);   // XCD swizzle (1024%8==0)
    const int bi = bid >> 5, bj = bid & 31;

    const short* gA = (const short*)Apb + (size_t)bi * 256 * 128;   // ic rows
    const short* gB = (const short*)Bpb + (size_t)bj * 256 * 128;   // jk rows

    // ---- stage both K-halves: 16 x global_load_lds(16B), pre-swizzled source.
    const int srow8 = lane >> 3;
    const int sgran = (lane & 7) ^ srow8;
    #pragma unroll
    for (int kh = 0; kh < 2; kh++) {
        #pragma unroll
        for (int rd = 0; rd < 4; rd++) {
            const int row = rd * 64 + wid * 8 + srow8;
            stage16(gB + row * 128 + kh * 64 + sgran * 8,
                    lds + kh * 65536 + rd * 8192 + wid * 1024);
            stage16(gA + row * 128 + kh * 64 + sgran * 8,
                    lds + kh * 65536 + 32768 + rd * 8192 + wid * 1024);
        }
    }

    asm volatile("s_waitcnt vmcnt(8)" ::: "memory");
    __builtin_amdgcn_s_barrier();

    f32x4 acc[8][4];
    #pragma unroll
    for (int mf = 0; mf < 8; mf++)
        #pragma unroll
        for (int nf = 0; nf < 4; nf++)
            acc[mf][nf] = (f32x4){0.f, 0.f, 0.f, 0.f};

    #pragma unroll
    for (int kh = 0; kh < 2; kh++) {
        if (kh) {
            asm volatile("s_waitcnt vmcnt(0)" ::: "memory");
            __builtin_amdgcn_s_barrier();
        }
        const char* sBb = lds + kh * 65536;
        const char* sAb = lds + kh * 65536 + 32768;
        #pragma unroll
        for (int ksl = 0; ksl < 2; ksl++) {
            short8 af[8], bfv[4];
            #pragma unroll
            for (int mf = 0; mf < 8; mf++) {
                const int row = wr * 128 + mf * 16 + r16;
                af[mf] = *(const short8*)(sBb + row * 128 + (((ksl * 4 + g) ^ (row & 7)) << 4));
            }
            #pragma unroll
            for (int nf = 0; nf < 4; nf++) {
                const int row = wc * 64 + nf * 16 + r16;
                bfv[nf] = *(const short8*)(sAb + row * 128 + (((ksl * 4 + g) ^ (row & 7)) << 4));
            }
            __builtin_amdgcn_s_setprio(1);
            #pragma unroll
            for (int mf = 0; mf < 8; mf++)
                #pragma unroll
                for (int nf = 0; nf < 4; nf++)
                    acc[mf][nf] = __builtin_amdgcn_mfma_f32_16x16x32_bf16(af[mf], bfv[nf], acc[mf][nf], 0, 0, 0);
            __builtin_amdgcn_s_setprio(0);
        }
    }
    __builtin_amdgcn_s_barrier();     // all A/B LDS reads done; sP may overwrite

    // ---- EPI roles: wave = (zgi, pg); 32 p-rows x 32 z per wave
    const int zgi = wid >> 1, pg = wid & 1;
    const int z0 = zgi * 32 + r16;
    const int z1 = zgi * 32 + 16 + r16;
    const short* wt = (const short*)WoutT;
    const short* wtz0 = wt + z0 * 1024 + g * 8;
    const short* wtz1 = wt + z1 * 1024 + g * 8;

    short8 Wr[4][2];
    #pragma unroll
    for (int d = 0; d < 4; d++) {
        Wr[d][0] = *(const short8*)&wtz0[d * 32];
        Wr[d][1] = *(const short8*)&wtz1[d * 32];
    }
    const float bv0 = bout[z0];
    const float bv1 = bout[z1];

    // ---- repack half h into sP[h]: p = i_loc*8 + j_loc, ck' = r16*32 + (mf&1)*16 + g*4 + reg
    #define REPACK(h)                                                                    \
        {                                                                                \
            char* sPh = lds + (h) * 65536;                                               \
            _Pragma("unroll")                                                            \
            for (int nq = 0; nq < 2; nq++) {                                             \
                const int nf = (h) + nq * 2;                                             \
                const int p = (wc * 2 + nq) * 8 + wr * 4;                                \
                _Pragma("unroll")                                                        \
                for (int mf = 0; mf < 8; mf++) {                                         \
                    const int pp = p + (mf >> 1);                                        \
                    const int L = r16 * 64 + (mf & 1) * 32 + g * 8;                      \
                    short4v v;                                                           \
                    v.x = f2bf(acc[mf][nf][0]); v.y = f2bf(acc[mf][nf][1]);              \
                    v.z = f2bf(acc[mf][nf][2]); v.w = f2bf(acc[mf][nf][3]);              \
                    *(short4v*)(sPh + pp * 1024 + (L ^ ((((L >> 7) ^ pp) & 7) << 4))) = v; \
                }                                                                        \
            }                                                                            \
        }

    REPACK(0)
    asm volatile("s_waitcnt lgkmcnt(0)" ::: "memory");
    __builtin_amdgcn_s_barrier();     // sP h0 visible
    REPACK(1)                          // h1 writes overlap h0 EPI

    f32x4 e00 = (f32x4){bv0, bv0, bv0, bv0};
    f32x4 e01 = (f32x4){bv1, bv1, bv1, bv1};
    f32x4 e10 = (f32x4){bv0, bv0, bv0, bv0};
    f32x4 e11 = (f32x4){bv1, bv1, bv1, bv1};

    const int row0 = pg * 32 + r16;
    const int row1 = pg * 32 + 16 + r16;
    const int k0 = (((0 >> 7) ^ row0) & 7), k1 = (((0 >> 7) ^ row1) & 7); // keys depend on L too; computed inline

    #define EPISTEP(ksg)                                                                 \
        {                                                                                \
            const char* sPh = lds + ((ksg) >> 4) * 65536;                                \
            const int L = ((ksg) & 15) * 64 + g * 16;                                    \
            short8 pv0 = *(const short8*)(sPh + row0 * 1024 +                            \
                                          (L ^ ((((L >> 7) ^ row0) & 7) << 4)));         \
            short8 pv1 = *(const short8*)(sPh + row1 * 1024 +                            \
                                          (L ^ ((((L >> 7) ^ row1) & 7) << 4)));         \
            __builtin_amdgcn_s_setprio(1);                                               \
            e00 = __builtin_amdgcn_mfma_f32_16x16x32_bf16(pv0, Wr[(ksg) & 3][0], e00, 0, 0, 0); \
            e01 = __builtin_amdgcn_mfma_f32_16x16x32_bf16(pv0, Wr[(ksg) & 3][1], e01, 0, 0, 0); \
            e10 = __builtin_amdgcn_mfma_f32_16x16x32_bf16(pv1, Wr[(ksg) & 3][0], e10, 0, 0, 0); \
            e11 = __builtin_amdgcn_mfma_f32_16x16x32_bf16(pv1, Wr[(ksg) & 3][1], e11, 0, 0, 0); \
            __builtin_amdgcn_s_setprio(0);                                               \
            if ((ksg) < 28) {                                                            \
                Wr[(ksg) & 3][0] = *(const short8*)&wtz0[((ksg) + 4) * 32];              \
                Wr[(ksg) & 3][1] = *(const short8*)&wtz1[((ksg) + 4) * 32];              \
            }                                                                            \
        }

    #pragma unroll
    for (int ksg = 0; ksg < 16; ksg++) EPISTEP(ksg)
    asm volatile("s_waitcnt lgkmcnt(0)" ::: "memory");
    __builtin_amdgcn_s_barrier();     // sP h1 visible
    #pragma unroll
    for (int ksg = 16; ksg < 32; ksg++) EPISTEP(ksg)

    // ---- store: p = pg*32 + pf*16 + g*4 + reg; ig = bi*8 + p>>3, jg = bj*8 + p&7
    #pragma unroll
    for (int reg = 0; reg < 4; reg++) {
        const int p0 = pg * 32 + g * 4 + reg;
        const int p1 = pg * 32 + 16 + g * 4 + reg;
        const size_t o0 = ((size_t)((bi * 8 + (p0 >> 3)) * 256 + bj * 8 + (p0 & 7))) * 128;
        const size_t o1 = ((size_t)((bi * 8 + (p1 >> 3)) * 256 + bj * 8 + (p1 & 7))) * 128;
        out[o0 + z0] = e00[reg] * (1.f / 128.f);
        out[o0 + z1] = e01[reg] * (1.f / 128.f);
        out[o1 + z0] = e10[reg] * (1.f / 128.f);
        out[o1 + z1] = e11[reg] * (1.f / 128.f);
    }
    #undef REPACK
    #undef EPISTEP
}

extern "C" void kernel_launch(void* const* d_in, const int* in_sizes, int n_in,
                              void* d_out, int out_size, void* d_ws, size_t ws_size,
                              hipStream_t stream) {
    const float* mm    = (const float*)d_in[0];
    const float* gamma = (const float*)d_in[1];
    const float* beta  = (const float*)d_in[2];
    const float* W1    = (const float*)d_in[3];
    const float* b1    = (const float*)d_in[4];
    const float* W2    = (const float*)d_in[5];
    const float* b2    = (const float*)d_in[6];
    const float* Wout  = (const float*)d_in[7];
    const float* bout  = (const float*)d_in[8];

    __hip_bfloat16* Ap    = (__hip_bfloat16*)((char*)d_ws + WS_A);
    __hip_bfloat16* Bp    = (__hip_bfloat16*)((char*)d_ws + WS_B);
    __hip_bfloat16* WoutT = (__hip_bfloat16*)((char*)d_ws + WS_WT);
    __hip_bfloat16* W12bf = (__hip_bfloat16*)((char*)d_ws + WS_W12);
    float* out = (float*)d_out;

    (void)hipFuncSetAttribute(reinterpret_cast<const void*>(k_gemm10),
                              hipFuncAttributeMaxDynamicSharedMemorySize, 131072);

    hipLaunchKernelGGL(k_prep, dim3(576), dim3(256), 0, stream, Wout, W1, W2, WoutT, W12bf);
    hipLaunchKernelGGL(k_lnproj, dim3(512), dim3(256), 0, stream,
                       mm, gamma, beta, b1, b2, W12bf, Ap, Bp);
    hipLaunchKernelGGL(k_gemm10, dim3(1024), dim3(512), 131072, stream,
                       Ap, Bp, WoutT, bout, out);
}

// Round 11
// 75.113 us; speedup vs baseline: 1.3229x; 1.3229x over previous
//
#include <hip/hip_runtime.h>
#include <hip/hip_bf16.h>

typedef __attribute__((ext_vector_type(8))) short short8;
typedef __attribute__((ext_vector_type(4))) short short4v;
typedef __attribute__((ext_vector_type(4))) float f32x4;

// ws: A' [8192][128] bf16 (2MB) | B' [8192][128] bf16 (2MB) |
//     WoutT [128][1024] bf16 (256KB) | W12bf [64][256] bf16 (32KB)
#define WS_A   0
#define WS_B   (8192 * 128 * 2)
#define WS_WT  (2 * 8192 * 128 * 2)
#define WS_W12 (WS_WT + 128 * 1024 * 2)

static __device__ __forceinline__ short f2bf(float x) {
    __hip_bfloat16 h = __float2bfloat16(x);
    return *reinterpret_cast<short*>(&h);
}

typedef __attribute__((address_space(3))) unsigned int lds_u32;
typedef const __attribute__((address_space(1))) unsigned int glb_u32;
static __device__ __forceinline__ void stage16(const void* g, void* l) {
    __builtin_amdgcn_global_load_lds((glb_u32*)g, (lds_u32*)l, 16, 0, 0);
}

// ---------------- Kernel 0: Wout -> bf16 [z][ck]; W1|W2 -> bf16 [64 c][256 d] ----------------
__global__ __launch_bounds__(256) void k_prep(const float* __restrict__ Wout,
                                              const float* __restrict__ W1,
                                              const float* __restrict__ W2,
                                              __hip_bfloat16* __restrict__ WoutT,
                                              __hip_bfloat16* __restrict__ W12bf) {
    int idx = blockIdx.x * 256 + threadIdx.x;
    if (blockIdx.x < 512) {
        int z = idx >> 10, ck = idx & 1023;
        WoutT[idx] = __float2bfloat16(Wout[ck * 128 + z]);
    } else {
        idx -= 512 * 256;                  // 0..16383
        int c = idx >> 8, d = idx & 255;
        W12bf[idx] = __float2bfloat16(c < 32 ? W1[d * 32 + c] : W2[d * 32 + (c - 32)]);
    }
}

// ---------------- Kernel 1: LayerNorm + dual projection via MFMA (unchanged) ----------------
__global__ __launch_bounds__(256) void k_lnproj(const float* __restrict__ mm,
                                                const float* __restrict__ gamma,
                                                const float* __restrict__ beta,
                                                const float* __restrict__ b1,
                                                const float* __restrict__ b2,
                                                const __hip_bfloat16* __restrict__ W12bf,
                                                __hip_bfloat16* __restrict__ Ap,
                                                __hip_bfloat16* __restrict__ Bp) {
    __shared__ char sMN[4][8192];      // per-wave [16 rows][256 d] bf16, XOR-swizzled
    __shared__ char sW[32768];         // [64 c][256 d] bf16, XOR-swizzled (512B rows)
    const int t    = threadIdx.x;
    const int lane = t & 63;
    const int wid  = t >> 6;
    const int gw   = blockIdx.x * 4 + wid;   // 0..2047
    const int i_   = gw & 255;
    const int sb   = (gw >> 8) * 16;

    #pragma unroll
    for (int it = 0; it < 8; it++) {
        const int idx = it * 256 + t;
        const int row = idx >> 5;
        const int L   = (idx & 31) * 16;
        *(short8*)(sW + row * 512 + (L ^ ((row & 7) << 4))) =
            *(const short8*)((const short*)W12bf + idx * 8);
    }

    float4 g4  = *(const float4*)&gamma[lane * 4];
    float4 be4 = *(const float4*)&beta[lane * 4];
    char* my = sMN[wid];

    #pragma unroll
    for (int rr = 0; rr < 16; rr++) {
        float4 x = *(const float4*)&mm[((size_t)(sb + rr) * 256 + i_) * 256 + lane * 4];
        float s  = x.x + x.y + x.z + x.w;
        float ss = x.x * x.x + x.y * x.y + x.z * x.z + x.w * x.w;
        #pragma unroll
        for (int off = 32; off; off >>= 1) {
            s  += __shfl_xor(s, off);
            ss += __shfl_xor(ss, off);
        }
        float mu  = s * (1.f / 256.f);
        float var = ss * (1.f / 256.f) - mu * mu;
        float rs  = rsqrtf(var + 1e-5f);
        short4v v;
        v.x = f2bf((x.x - mu) * rs * g4.x + be4.x);
        v.y = f2bf((x.y - mu) * rs * g4.y + be4.y);
        v.z = f2bf((x.z - mu) * rs * g4.z + be4.z);
        v.w = f2bf((x.w - mu) * rs * g4.w + be4.w);
        *(short4v*)(my + rr * 512 + ((lane * 8) ^ ((rr & 7) << 4))) = v;
    }
    __syncthreads();

    const int g = lane >> 4, r16 = lane & 15;

    f32x4 acc[4];
    #pragma unroll
    for (int nf = 0; nf < 4; nf++) {
        int col = nf * 16 + r16;
        float bv = (col < 32) ? b1[col] : b2[col - 32];
        acc[nf] = (f32x4){bv, bv, bv, bv};
    }
    #pragma unroll
    for (int ks = 0; ks < 8; ks++) {
        const int L = ks * 64 + g * 16;
        short8 af = *(const short8*)(my + r16 * 512 + (L ^ ((r16 & 7) << 4)));
        #pragma unroll
        for (int nf = 0; nf < 4; nf++) {
            short8 bfv = *(const short8*)(sW + (nf * 16 + r16) * 512 + (L ^ ((r16 & 7) << 4)));
            acc[nf] = __builtin_amdgcn_mfma_f32_16x16x32_bf16(af, bfv, acc[nf], 0, 0, 0);
        }
    }
    #pragma unroll
    for (int nf = 0; nf < 4; nf++) {
        int col = nf * 16 + r16;
        short* Out = (short*)((col < 32) ? Ap : Bp);
        int cr = col & 31;
        short4v v;
        v.x = f2bf(acc[nf][0]); v.y = f2bf(acc[nf][1]);
        v.z = f2bf(acc[nf][2]); v.w = f2bf(acc[nf][3]);
        *(short4v*)&Out[(i_ * 32 + cr) * 128 + sb + g * 4] = v;
    }
}

// ---------------- Kernel 2: 256x256 tile, 1024 threads (16 waves, 4/SIMD) ----------------
// LDS (128KB dyn): staging kh0 [0,64K) (B 32K | A 32K), kh1 [64K,128K).
// After main: sP h0 [0,64K), h1 [64K,128K) ([64 p][512 ck'] each, key ((L>>7)^p)&7).
// Main: 4x4 waves of 64x64 (acc[4][4] = 64 AGPR -> fits 128-reg budget).
// EPI: wave = (ih = wid>>3 ck-half, zset = wid&7 -> 16 z); halves run in PARALLEL;
// symmetric 32KB pair-reduction; each wave stores 2 of 4 p-frags.
extern __shared__ char lds[];

__global__ __launch_bounds__(1024, 4) void k_gemm11(const __hip_bfloat16* __restrict__ Apb,
                                                    const __hip_bfloat16* __restrict__ Bpb,
                                                    const __hip_bfloat16* __restrict__ WoutT,
                                                    const float* __restrict__ bout,
                                                    float* __restrict__ out) {
    const int t = threadIdx.x, lane = t & 63, wid = t >> 6;
    const int g = lane >> 4, r16 = lane & 15;
    const int wr = wid >> 2, wc = wid & 3;            // jk quarter, ic quarter (64 rows each)
    const int bid = (blockIdx.x & 7) * 128 + (blockIdx.x >> 3);   // XCD swizzle (1024%8==0)
    const int bi = bid >> 5, bj = bid & 31;

    const short* gA = (const short*)Apb + (size_t)bi * 256 * 128;   // ic rows
    const short* gB = (const short*)Bpb + (size_t)bj * 256 * 128;   // jk rows

    // ---- stage both K-halves: 8 x global_load_lds(16B)/thread, pre-swizzled source.
    const int srow8 = lane >> 3;
    const int sgran = (lane & 7) ^ srow8;
    #pragma unroll
    for (int kh = 0; kh < 2; kh++) {
        #pragma unroll
        for (int it = 0; it < 2; it++) {
            const int row = it * 128 + wid * 8 + srow8;
            stage16(gB + row * 128 + kh * 64 + sgran * 8,
                    lds + kh * 65536 + it * 16384 + wid * 1024);
        }
        #pragma unroll
        for (int it = 0; it < 2; it++) {
            const int row = it * 128 + wid * 8 + srow8;
            stage16(gA + row * 128 + kh * 64 + sgran * 8,
                    lds + kh * 65536 + 32768 + it * 16384 + wid * 1024);
        }
    }

    asm volatile("s_waitcnt vmcnt(4)" ::: "memory");   // kh0 staged
    __builtin_amdgcn_s_barrier();

    f32x4 acc[4][4];
    #pragma unroll
    for (int mf = 0; mf < 4; mf++)
        #pragma unroll
        for (int nf = 0; nf < 4; nf++)
            acc[mf][nf] = (f32x4){0.f, 0.f, 0.f, 0.f};

    #pragma unroll
    for (int kh = 0; kh < 2; kh++) {
        if (kh) {
            asm volatile("s_waitcnt vmcnt(0)" ::: "memory");
            __builtin_amdgcn_s_barrier();
        }
        const char* sBb = lds + kh * 65536;
        const char* sAb = lds + kh * 65536 + 32768;
        #pragma unroll
        for (int ksl = 0; ksl < 2; ksl++) {
            short8 af[4], bfv[4];
            #pragma unroll
            for (int mf = 0; mf < 4; mf++) {
                const int row = wr * 64 + mf * 16 + r16;
                af[mf] = *(const short8*)(sBb + row * 128 + (((ksl * 4 + g) ^ (row & 7)) << 4));
            }
            #pragma unroll
            for (int nf = 0; nf < 4; nf++) {
                const int row = wc * 64 + nf * 16 + r16;
                bfv[nf] = *(const short8*)(sAb + row * 128 + (((ksl * 4 + g) ^ (row & 7)) << 4));
            }
            __builtin_amdgcn_s_setprio(1);
            #pragma unroll
            for (int mf = 0; mf < 4; mf++)
                #pragma unroll
                for (int nf = 0; nf < 4; nf++)
                    acc[mf][nf] = __builtin_amdgcn_mfma_f32_16x16x32_bf16(af[mf], bfv[nf], acc[mf][nf], 0, 0, 0);
            __builtin_amdgcn_s_setprio(0);
        }
    }
    asm volatile("s_waitcnt lgkmcnt(0)" ::: "memory");
    __builtin_amdgcn_s_barrier();     // all A/B LDS reads done; sP may overwrite

    // ---- EPI roles + W prefetch (VMEM overlaps repack)
    const int ih = wid >> 3, zset = wid & 7;
    const int z = zset * 16 + r16;
    const short* wtz = (const short*)WoutT + z * 1024 + ih * 512 + g * 8;
    short8 Wr[4];
    #pragma unroll
    for (int d = 0; d < 4; d++) Wr[d] = *(const short8*)&wtz[d * 32];
    const float bv = (ih == 0) ? bout[z] : 0.f;

    // ---- repack BOTH halves -> sP (16 b64 writes/thread; key verified 4-way floor)
    #pragma unroll
    for (int h = 0; h < 2; h++) {
        char* sPh = lds + h * 65536;
        #pragma unroll
        for (int nq = 0; nq < 2; nq++) {
            const int nf = h + nq * 2;
            #pragma unroll
            for (int mf = 0; mf < 4; mf++) {
                const int pp = (wc * 2 + nq) * 8 + wr * 2 + (mf >> 1);
                const int L = r16 * 64 + (mf & 1) * 32 + g * 8;
                short4v v;
                v.x = f2bf(acc[mf][nf][0]); v.y = f2bf(acc[mf][nf][1]);
                v.z = f2bf(acc[mf][nf][2]); v.w = f2bf(acc[mf][nf][3]);
                *(short4v*)(sPh + pp * 1024 + (L ^ ((((L >> 7) ^ pp) & 7) << 4))) = v;
            }
        }
    }
    asm volatile("s_waitcnt lgkmcnt(0)" ::: "memory");
    __builtin_amdgcn_s_barrier();     // sP complete

    // ---- EPI: both ck-halves in parallel. 16 ks x 4 pf per wave; rolling Wr[4].
    const char* sPh = lds + ih * 65536;
    f32x4 e[4];
    #pragma unroll
    for (int pf = 0; pf < 4; pf++) e[pf] = (f32x4){bv, bv, bv, bv};

    #pragma unroll
    for (int ks = 0; ks < 16; ks++) {
        const int L = ks * 64 + g * 16;
        short8 pv[4];
        #pragma unroll
        for (int pf = 0; pf < 4; pf++) {
            const int row = pf * 16 + r16;
            pv[pf] = *(const short8*)(sPh + row * 1024 + (L ^ ((((L >> 7) ^ row) & 7) << 4)));
        }
        __builtin_amdgcn_s_setprio(1);
        #pragma unroll
        for (int pf = 0; pf < 4; pf++)
            e[pf] = __builtin_amdgcn_mfma_f32_16x16x32_bf16(pv[pf], Wr[ks & 3], e[pf], 0, 0, 0);
        __builtin_amdgcn_s_setprio(0);
        if (ks < 12) Wr[ks & 3] = *(const short8*)&wtz[(ks + 4) * 32];
    }
    asm volatile("s_waitcnt lgkmcnt(0)" ::: "memory");
    __builtin_amdgcn_s_barrier();     // all sP reads done; reduction buffer may overwrite

    // ---- symmetric pair reduction (32KB at [0,32K)):
    // slot(ih, zset, q) = ih*16384 + zset*2048 + q*1024 + lane*16.
    // ih=0 exports e[2],e[3] (q=0,1); ih=1 exports e[0],e[1] (q=0,1).
    {
        char* wbase = lds + ih * 16384 + zset * 2048 + lane * 16;
        const int pf0 = ih ? 0 : 2;
        *(f32x4*)(wbase)        = e[pf0];
        *(f32x4*)(wbase + 1024) = e[pf0 + 1];
    }
    asm volatile("s_waitcnt lgkmcnt(0)" ::: "memory");
    __builtin_amdgcn_s_barrier();

    {
        const char* rbase = lds + (ih ? 0 : 16384) + zset * 2048 + lane * 16;
        const int pfs = ih ? 2 : 0;
        #pragma unroll
        for (int q = 0; q < 2; q++) {
            f32x4 o = *(const f32x4*)(rbase + q * 1024);
            const int pf = pfs + q;
            #pragma unroll
            for (int reg = 0; reg < 4; reg++) {
                const int p = pf * 16 + g * 4 + reg;
                out[((size_t)((bi * 8 + (p >> 3)) * 256 + bj * 8 + (p & 7))) * 128 + z] =
                    (e[pf][reg] + o[reg]) * (1.f / 128.f);
            }
        }
    }
}

extern "C" void kernel_launch(void* const* d_in, const int* in_sizes, int n_in,
                              void* d_out, int out_size, void* d_ws, size_t ws_size,
                              hipStream_t stream) {
    const float* mm    = (const float*)d_in[0];
    const float* gamma = (const float*)d_in[1];
    const float* beta  = (const float*)d_in[2];
    const float* W1    = (const float*)d_in[3];
    const float* b1    = (const float*)d_in[4];
    const float* W2    = (const float*)d_in[5];
    const float* b2    = (const float*)d_in[6];
    const float* Wout  = (const float*)d_in[7];
    const float* bout  = (const float*)d_in[8];

    __hip_bfloat16* Ap    = (__hip_bfloat16*)((char*)d_ws + WS_A);
    __hip_bfloat16* Bp    = (__hip_bfloat16*)((char*)d_ws + WS_B);
    __hip_bfloat16* WoutT = (__hip_bfloat16*)((char*)d_ws + WS_WT);
    __hip_bfloat16* W12bf = (__hip_bfloat16*)((char*)d_ws + WS_W12);
    float* out = (float*)d_out;

    (void)hipFuncSetAttribute(reinterpret_cast<const void*>(k_gemm11),
                              hipFuncAttributeMaxDynamicSharedMemorySize, 131072);

    hipLaunchKernelGGL(k_prep, dim3(576), dim3(256), 0, stream, Wout, W1, W2, WoutT, W12bf);
    hipLaunchKernelGGL(k_lnproj, dim3(512), dim3(256), 0, stream,
                       mm, gamma, beta, b1, b2, W12bf, Ap, Bp);
    hipLaunchKernelGGL(k_gemm11, dim3(1024), dim3(1024), 131072, stream,
                       Ap, Bp, WoutT, bout, out);
}